// Round 13
// baseline (199.214 us; speedup 1.0000x reference)
//
#include <hip/hip_runtime.h>
#include <math.h>

#define DIM 1024
#define NH 16
#define HD 64
#define TT 2048
#define NTOK 4096   // B*T

typedef __bf16 bf8v __attribute__((ext_vector_type(8)));
typedef float f4v __attribute__((ext_vector_type(4)));
typedef float f16v __attribute__((ext_vector_type(16)));
typedef unsigned short us8 __attribute__((ext_vector_type(8)));
typedef unsigned short us4 __attribute__((ext_vector_type(4)));
typedef unsigned int u4v __attribute__((ext_vector_type(4)));

static __device__ __forceinline__ unsigned short f2bf(float f) {
    unsigned int u = __float_as_uint(f);
    u += 0x7FFFu + ((u >> 16) & 1u);   // RNE
    return (unsigned short)(u >> 16);
}
static __device__ __forceinline__ bf8v ld8(const unsigned short* p) {
    return __builtin_bit_cast(bf8v, *(const us8*)p);
}
// async global->LDS, 16B per lane; HW dest = wave-uniform base + lane*16
static __device__ __forceinline__ void gl_lds(const unsigned short* g, unsigned short* l) {
    __builtin_amdgcn_global_load_lds((const __attribute__((address_space(1))) unsigned int*)(g),
                                     (__attribute__((address_space(3))) unsigned int*)(l), 16, 0, 0);
}

// ---------- fused prep: x->bf16 | W transpose->bf16 | rope table | zero Rm ----------
__global__ void k_prep(const float* __restrict__ x, unsigned short* __restrict__ xb,
                       const float* __restrict__ Wq, const float* __restrict__ Wk,
                       const float* __restrict__ Wv, unsigned short* __restrict__ wt,
                       float* __restrict__ rope, float* __restrict__ Rm) {
    int tid = threadIdx.x;
    int bb = blockIdx.x;
    if (bb < 4096) {                       // cast x (4 floats/thread)
        int i = bb * 256 + tid;
        float4 v = ((const float4*)x)[i];
        us4 o;
        o[0] = f2bf(v.x); o[1] = f2bf(v.y); o[2] = f2bf(v.z); o[3] = f2bf(v.w);
        *(us4*)&xb[i * 4] = o;
    } else if (bb < 7168) {                // transpose Wq|Wk|Wv
        __shared__ float tile[32][33];
        bb -= 4096;
        int z = bb >> 10, rem = bb & 1023;
        int bx = rem & 31, by = rem >> 5;
        const float* W = (z == 0) ? Wq : ((z == 1) ? Wk : Wv);
        int tx = tid & 31, ty = tid >> 5;   // (32, 8)
        int c0 = bx * 32, k0 = by * 32;
#pragma unroll
        for (int j = 0; j < 4; j++)
            tile[ty + j * 8][tx] = W[(k0 + ty + j * 8) * DIM + c0 + tx];
        __syncthreads();
        unsigned short* out = wt + z * DIM * DIM;
#pragma unroll
        for (int j = 0; j < 4; j++)
            out[(c0 + ty + j * 8) * DIM + k0 + tx] = f2bf(tile[tx][ty + j * 8]);
    } else if (bb < 7680) {                // rope [TT][HD]
        int i = (bb - 7168) * 256 + tid;
        int s = i >> 6, d = i & 63;
        float inv = exp2f(-(float)(d & 31) * (13.287712379549449f / 32.0f));
        float a = (float)s * inv;
        rope[i] = (d < 32) ? cosf(a) : sinf(a);
    } else {                               // zero Rm (4096 floats) for k_R atomics
        Rm[(bb - 7680) * 256 + tid] = 0.f;
    }
}

// ---------------- R = rope^T rope (64x64), 8x s-parallel blocks, atomic partials ----------------
__global__ void k_R(const float* __restrict__ rope, float* __restrict__ R) {
    __shared__ float red[256];
    int d = blockIdx.x & 63, sg = blockIdx.x >> 6;    // 64 d x 8 s-groups
    int e = threadIdx.x & 63, sl = threadIdx.x >> 6;
    const float* rp = rope + (sg * 256 + sl * 64) * 64;
    float acc = 0.f;
    for (int s = 0; s < 64; s++)
        acc += rp[s * 64 + d] * rp[s * 64 + e];
    red[threadIdx.x] = acc;
    __syncthreads();
    if (sl == 0)
        atomicAdd(&R[d * 64 + e], (red[e] + red[e + 64]) + (red[e + 128] + red[e + 192]));
}

// ------------- Wo2t[j][r] = sum_e R[d][e] * Wo[h*64+e][j],  r = h*64+d -------------
__global__ void k_wo2(const float* __restrict__ Wo, const float* __restrict__ R,
                      unsigned short* __restrict__ wo2t) {
    __shared__ float Ws[64 * 65];   // Ws[e][j]
    __shared__ float Rt[64 * 65];   // Rt[e][d] = R[d*64+e]
    int tid = threadIdx.x;
    int h = blockIdx.y, j0 = blockIdx.x * 64;
    for (int idx = tid; idx < 4096; idx += 256) {
        int e = idx >> 6, j = idx & 63;
        Ws[e * 65 + j] = Wo[(h * 64 + e) * DIM + j0 + j];
        Rt[e * 65 + j] = R[j * 64 + e];
    }
    __syncthreads();
    int d = tid & 63, jb = (tid >> 6) * 16;
    float acc[16] = {};
    for (int e = 0; e < 64; e++) {
        float r = Rt[e * 65 + d];
#pragma unroll
        for (int jj = 0; jj < 16; jj++)
            acc[jj] += r * Ws[e * 65 + jb + jj];
    }
#pragma unroll
    for (int jj = 0; jj < 16; jj++)
        wo2t[(j0 + jb + jj) * DIM + h * 64 + d] = f2bf(acc[jj]);
}

// ================= GEMM cores v3: 128-thread blocks (2 waves), m97 staging, XOR-swizzled LDS =================
// Same per-wave phase work as the proven 256-thr version (16 or 8 MFMA : 8 or 6 ds_read), but
// 2x the independent barrier groups per CU (the round-4/round-9 mechanism).
// LDS tile [R][32] bf16: chunk c -> row r=c>>2, phys slot c&3 holds logical (c&3)^(r&3)
// (involution via inverse-swizzled global source); frag read slot qx = quad^(l16&3).

// QKV projection: BM=64, BN=128, grid 1536 (6 blocks/CU), XCD-grouped (3 n-panels per XCD).
// Q (pre-scaled by c1), K scatter to [B][H][T][64]; V TRANSPOSED to [B][H][64][T].
__global__ __launch_bounds__(128, 3) void k_gemm_qkv(const unsigned short* __restrict__ A,
                                                     const unsigned short* __restrict__ Bt,
                                                     unsigned short* __restrict__ qk,
                                                     unsigned short* __restrict__ vt) {
    __shared__ unsigned short As[64 * 32];
    __shared__ unsigned short Bs[128 * 32];
    const int K = 1024;
    int tid = threadIdx.x;               // 0..127
    int lane = tid & 63, w = tid >> 6;   // w 0/1
    int quad = lane >> 4, l16 = lane & 15;
    int bid = blockIdx.x;
    int xcd = bid & 7, s = bid >> 3;     // s 0..191
    int n0 = (xcd * 3 + (s % 3)) * 128;  // 24 n-panels, 3 per XCD
    int m0 = (s / 3) * 64;               // 64 m-panels
    int wn = w * 64;                     // wave covers 64 rows x 64 cols

    // staging: A 256 chunks (2/thread), B 512 chunks (4/thread)
    int offA[2], dstA[2], offB[4], dstB[4];
#pragma unroll
    for (int j = 0; j < 2; j++) {
        int c = tid + 128 * j;
        int r = c >> 2, cc = ((c & 3) ^ (r & 3)) * 8;
        offA[j] = r * K + cc;
        dstA[j] = c * 8;
    }
#pragma unroll
    for (int j = 0; j < 4; j++) {
        int c = tid + 128 * j;
        int r = c >> 2, cc = ((c & 3) ^ (r & 3)) * 8;
        offB[j] = r * K + cc;
        dstB[j] = c * 8;
    }
    const unsigned short* Ab = A + m0 * K;
    const unsigned short* Bb = Bt + n0 * K;
    int qx = quad ^ (l16 & 3);

    f4v acc[4][4] = {};
    for (int k0 = 0; k0 < K; k0 += 32) {
        __syncthreads();                       // prior iter frag reads done
#pragma unroll
        for (int j = 0; j < 2; j++)
            gl_lds(Ab + offA[j] + k0, &As[dstA[j]]);
#pragma unroll
        for (int j = 0; j < 4; j++)
            gl_lds(Bb + offB[j] + k0, &Bs[dstB[j]]);
        __syncthreads();                       // drains vmcnt -> tiles in LDS
        bf8v af[4], bf[4];
#pragma unroll
        for (int mt = 0; mt < 4; mt++)
            af[mt] = ld8(&As[(mt * 16 + l16) * 32 + qx * 8]);
#pragma unroll
        for (int nt = 0; nt < 4; nt++)
            bf[nt] = ld8(&Bs[(wn + nt * 16 + l16) * 32 + qx * 8]);
#pragma unroll
        for (int mt = 0; mt < 4; mt++)
#pragma unroll
            for (int nt = 0; nt < 4; nt++)
                acc[mt][nt] = __builtin_amdgcn_mfma_f32_16x16x32_bf16(af[mt], bf[nt], acc[mt][nt], 0, 0, 0);
    }
#pragma unroll
    for (int mt = 0; mt < 4; mt++) {
#pragma unroll
        for (int nt = 0; nt < 4; nt++) {
            int gc = n0 + wn + nt * 16 + l16;
            int h = (gc >> 6) & 15;
            int d = gc & 63;
            if (gc < 2048) {             // Q or K: [mtx][B][H][T][64]; Q pre-scaled by c1
                float qs = (gc < 1024) ? 0.18033688011111793f : 1.0f;
                int mtx = gc >> 10;
                unsigned short* base = qk + mtx * (NTOK * DIM);
#pragma unroll
                for (int r = 0; r < 4; r++) {
                    int gm = m0 + mt * 16 + quad * 4 + r;
                    int b = gm >> 11, t = gm & 2047;
                    base[((b * NH + h) * TT + t) * HD + d] = f2bf(acc[mt][nt][r] * qs);
                }
            } else {                     // V: transposed [B][H][64][T]
                int gm0 = m0 + mt * 16 + quad * 4;
                int b = gm0 >> 11, t = gm0 & 2047;
                us4 ov;
#pragma unroll
                for (int r = 0; r < 4; r++)
                    ov[r] = f2bf(acc[mt][nt][r]);
                *(us4*)&vt[(((b * NH + h) * HD) + d) * TT + t] = ov;
            }
        }
    }
}

// Output projection v5: BM=64, BN=64, grid 1024 (4 blocks/CU), XCD-grouped (8 m-panels/XCD).
__global__ __launch_bounds__(128, 4) void k_gemm_out(const unsigned short* __restrict__ A,
                                                     const unsigned short* __restrict__ Bt,
                                                     const float* __restrict__ bo,
                                                     float* __restrict__ out) {
    __shared__ unsigned short As[64 * 32];
    __shared__ unsigned short Bs[64 * 32];
    const int K = 1024;
    int tid = threadIdx.x;               // 0..127
    int lane = tid & 63, w = tid >> 6;   // w 0/1
    int quad = lane >> 4, l16 = lane & 15;
    int bid = blockIdx.x;
    int xcd = bid & 7, slot = bid >> 3;  // slot 0..127
    int y = xcd * 8 + (slot & 7);        // m-panel 0..63
    int x = slot >> 3;                   // n-panel 0..15
    int m0 = y * 64, n0 = x * 64;
    int wn = w * 32;                     // wave covers 64 rows x 32 cols

    // staging: A and B each 256 chunks (2/thread)
    int off[2], dst[2];
#pragma unroll
    for (int j = 0; j < 2; j++) {
        int c = tid + 128 * j;
        int r = c >> 2, cc = ((c & 3) ^ (r & 3)) * 8;
        off[j] = r * K + cc;
        dst[j] = c * 8;
    }
    const unsigned short* Ab = A + m0 * K;
    const unsigned short* Bb = Bt + n0 * K;
    int qx = quad ^ (l16 & 3);

    f4v acc[4][2] = {};
    for (int k0 = 0; k0 < K; k0 += 32) {
        __syncthreads();                       // prior iter frag reads done
#pragma unroll
        for (int j = 0; j < 2; j++)
            gl_lds(Ab + off[j] + k0, &As[dst[j]]);
#pragma unroll
        for (int j = 0; j < 2; j++)
            gl_lds(Bb + off[j] + k0, &Bs[dst[j]]);
        __syncthreads();                       // drains vmcnt -> tiles in LDS
        bf8v af[4], bf[2];
#pragma unroll
        for (int mt = 0; mt < 4; mt++)
            af[mt] = ld8(&As[(mt * 16 + l16) * 32 + qx * 8]);
#pragma unroll
        for (int nt = 0; nt < 2; nt++)
            bf[nt] = ld8(&Bs[(wn + nt * 16 + l16) * 32 + qx * 8]);
#pragma unroll
        for (int mt = 0; mt < 4; mt++)
#pragma unroll
            for (int nt = 0; nt < 2; nt++)
                acc[mt][nt] = __builtin_amdgcn_mfma_f32_16x16x32_bf16(af[mt], bf[nt], acc[mt][nt], 0, 0, 0);
    }
#pragma unroll
    for (int mt = 0; mt < 4; mt++) {
#pragma unroll
        for (int nt = 0; nt < 2; nt++) {
            int gc = n0 + wn + nt * 16 + l16;
            float bias = bo[gc];
#pragma unroll
            for (int r = 0; r < 4; r++) {
                int gm = m0 + mt * 16 + quad * 4 + r;
                out[gm * DIM + gc] = acc[mt][nt][r] + bias;
            }
        }
    }
}

// ================= flash attention v6 (round-10 proven): full-KV, direct normalized output =================
// Each block iterates all 2048 keys (32 iters); softmax rows complete in-register -> normalize
// by rcp(lsum), write FINAL bf16 attn directly. Grid 512 (2 blocks/CU). UNCHANGED from round 10.
__global__ __launch_bounds__(256, 2) void k_flash(const unsigned short* __restrict__ qk,
                                                  const unsigned short* __restrict__ vt,
                                                  unsigned short* __restrict__ attn) {
    __shared__ unsigned short Ks[2][64 * 64];
    __shared__ unsigned short Vs[2][64 * 64];
    int tid = threadIdx.x;
    int lane = tid & 63, w = tid >> 6;
    int q31 = lane & 31, hi = lane >> 5;
    int bid = blockIdx.x;
    int xcd = bid & 7, sl = bid >> 3;
    int bh = xcd * 4 + (sl & 3);
    int qt = sl >> 2;                    // 0..15

    const unsigned short* Qg = qk + bh * (TT * HD);
    const unsigned short* Kg = qk + NTOK * DIM + bh * (TT * HD);
    const unsigned short* Vg = vt + bh * (HD * TT);

    // Q B-frag (k=dim): lane n=q31 holds Q[qrow][16*ks + 8*hi + j]
    int qrow = qt * 128 + w * 32 + q31;
    bf8v qf[4];
#pragma unroll
    for (int ks = 0; ks < 4; ks++)
        qf[ks] = ld8(Qg + qrow * HD + ks * 16 + hi * 8);

    // staging: 512 chunks of 16B per tile; thread stages chunks tid and 256+tid.
    // chunk idx -> row r=idx>>3, phys slot p=idx&7, logical chunk c=p^(r&7) (involution).
    int r0 = tid >> 3, sw = (tid & 7) ^ (r0 & 7);
    int offK0 = r0 * HD + sw * 8, offK1 = offK0 + 32 * HD;
    int offV0 = r0 * TT + sw * 8, offV1 = offV0 + 32 * TT;
    int dst0 = tid * 8, dst1 = dst0 + 2048;

#define STAGE(tile, bufsel) do {                                  \
        const unsigned short* kb_ = Kg + (tile) * 64 * HD;        \
        const unsigned short* vb_ = Vg + (tile) * 64;             \
        gl_lds(kb_ + offK0, &Ks[bufsel][dst0]);                   \
        gl_lds(kb_ + offK1, &Ks[bufsel][dst1]);                   \
        gl_lds(vb_ + offV0, &Vs[bufsel][dst0]);                   \
        gl_lds(vb_ + offV1, &Vs[bufsel][dst1]);                   \
    } while (0)

    STAGE(0, 0);
    STAGE(1, 1);

    f16v oacc[2] = {};               // [mtd] O^T dim tiles
    float lsg = 0.f;
    int xsw = q31 & 7;

    for (int it = 0; it < 32; it++) {
        int cur = it & 1;
        if (it == 31) { asm volatile("s_waitcnt vmcnt(0)" ::: "memory"); }
        else          { asm volatile("s_waitcnt vmcnt(4)" ::: "memory"); }
        __builtin_amdgcn_s_barrier();
        asm volatile("" ::: "memory");

        const unsigned short* Kb = Ks[cur];
        const unsigned short* Vb = Vs[cur];

        // K frags + QK^T: S^T[key][qrow], 2 key tiles x K=64 (4 steps)
        bf8v kf0[4], kf1[4];
#pragma unroll
        for (int ks = 0; ks < 4; ks++) {
            kf0[ks] = ld8(&Kb[(q31) * 64 + ((2 * ks + hi) ^ xsw) * 8]);
            kf1[ks] = ld8(&Kb[(32 + q31) * 64 + ((2 * ks + hi) ^ xsw) * 8]);
        }
        f16v s0 = {}, s1 = {};
#pragma unroll
        for (int ks = 0; ks < 4; ks++) {
            s0 = __builtin_amdgcn_mfma_f32_32x32x16_bf16(kf0[ks], qf[ks], s0, 0, 0, 0);
            s1 = __builtin_amdgcn_mfma_f32_32x32x16_bf16(kf1[ks], qf[ks], s1, 0, 0, 0);
        }

        // V^T A-frags (ds_read latency hides under softmax chunks)
        bf8v vf[2][4];
#pragma unroll
        for (int kk = 0; kk < 4; kk++) {
            vf[0][kk] = ld8(&Vb[(q31) * 64 + ((2 * kk + hi) ^ xsw) * 8]);
            vf[1][kk] = ld8(&Vb[(32 + q31) * 64 + ((2 * kk + hi) ^ xsw) * 8]);
        }

        // chunk-fused softmax -> PV. Per 16-key chunk kk = mt*2+sub:
        // reg r of s_mt holds S^T[key = 32mt + (r&3)+8(r>>2)+4hi][qrow]; p = 2^s (Q pre-scaled).
        // cvt_pk pairs -> e0..e3 (keys {0,1},{2,3},{8,9},{10,11}+4hi); swap(e0,e2)+swap(e1,e3)
        // -> P^T B-frag words (k=8hi+j). Then 2 PV MFMAs for this chunk overlap next chunk VALU.
#pragma unroll
        for (int mt = 0; mt < 2; mt++) {
#pragma unroll
            for (int sub = 0; sub < 2; sub++) {
                const f16v& s = mt ? s1 : s0;
                float pe[8];
#pragma unroll
                for (int j = 0; j < 8; j++)
                    pe[j] = __builtin_amdgcn_exp2f(s[sub * 8 + j]);
                float t01 = pe[0] + pe[1], t23 = pe[2] + pe[3];
                float t45 = pe[4] + pe[5], t67 = pe[6] + pe[7];
                lsg += (t01 + t23) + (t45 + t67);
                unsigned int e0, e1, e2, e3;
                asm("v_cvt_pk_bf16_f32 %0, %1, %2" : "=v"(e0) : "v"(pe[0]), "v"(pe[1]));
                asm("v_cvt_pk_bf16_f32 %0, %1, %2" : "=v"(e1) : "v"(pe[2]), "v"(pe[3]));
                asm("v_cvt_pk_bf16_f32 %0, %1, %2" : "=v"(e2) : "v"(pe[4]), "v"(pe[5]));
                asm("v_cvt_pk_bf16_f32 %0, %1, %2" : "=v"(e3) : "v"(pe[6]), "v"(pe[7]));
                asm("v_permlane32_swap_b32 %0, %1" : "+v"(e0), "+v"(e2));
                asm("v_permlane32_swap_b32 %0, %1" : "+v"(e1), "+v"(e3));
                u4v pv = {e0, e1, e2, e3};
                bf8v pb = __builtin_bit_cast(bf8v, pv);
                int kk = mt * 2 + sub;
                oacc[0] = __builtin_amdgcn_mfma_f32_32x32x16_bf16(vf[0][kk], pb, oacc[0], 0, 0, 0);
                oacc[1] = __builtin_amdgcn_mfma_f32_32x32x16_bf16(vf[1][kk], pb, oacc[1], 0, 0, 0);
            }
        }

        __builtin_amdgcn_s_barrier();
        asm volatile("" ::: "memory");
        if (it < 30) STAGE(it + 2, cur);
    }
#undef STAGE

    // epilogue: complete row sums -> normalize in-register, write FINAL bf16 attn
    float lsum = lsg + __shfl_xor(lsg, 32, 64);
    float inv = __builtin_amdgcn_rcpf(lsum);
    int b = bh >> 4, h = bh & 15;
    unsigned short* dst = attn + ((b * TT) + qrow) * DIM + h * HD + hi * 4;
#pragma unroll
    for (int mtd = 0; mtd < 2; mtd++) {
#pragma unroll
        for (int g4 = 0; g4 < 4; g4++) {
            us4 ov;
#pragma unroll
            for (int r = 0; r < 4; r++)
                ov[r] = f2bf(oacc[mtd][g4 * 4 + r] * inv);   // dim = 32*mtd + 8*g4 + 4*hi + r
            *(us4*)&dst[mtd * 32 + g4 * 8] = ov;
        }
    }
}

extern "C" void kernel_launch(void* const* d_in, const int* in_sizes, int n_in,
                              void* d_out, int out_size, void* d_ws, size_t ws_size,
                              hipStream_t stream) {
    const float* x  = (const float*)d_in[0];
    const float* Wq = (const float*)d_in[1];
    const float* Wk = (const float*)d_in[2];
    const float* Wv = (const float*)d_in[3];
    const float* Wo = (const float*)d_in[4];
    const float* bo = (const float*)d_in[5];
    float* out = (float*)d_out;
    char* ws = (char*)d_ws;

    // attn (8MB) aliases Xb: Xb dead after k_gemm_qkv, flash writes attn after.
    unsigned short* Xb    = (unsigned short*)(ws);                 //  8 MB
    unsigned short* Wqkvt = (unsigned short*)(ws + 8388608);       //  6 MB
    unsigned short* attn  = (unsigned short*)(ws);                 //  8 MB (aliases Xb)
    unsigned short* QK    = (unsigned short*)(ws + 16777216);      // 16 MB (Q then K)
    unsigned short* Vt    = (unsigned short*)(ws + 33554432);      //  8 MB (V transposed)
    unsigned short* Wo2t  = (unsigned short*)(ws + 50331648);      //  2 MB
    float*          rope  = (float*)(ws + 52428800);               // 512 KB
    float*          Rm    = (float*)(ws + 52953088);               // 16 KB

    hipLaunchKernelGGL(k_prep,     dim3(7696),   dim3(256), 0, stream, x, Xb, Wq, Wk, Wv, Wqkvt, rope, Rm);
    hipLaunchKernelGGL(k_R,        dim3(512),    dim3(256), 0, stream, rope, Rm);
    hipLaunchKernelGGL(k_wo2,      dim3(16, 16), dim3(256), 0, stream, Wo, Rm, Wo2t);
    hipLaunchKernelGGL(k_gemm_qkv, dim3(1536),   dim3(128), 0, stream, Xb, Wqkvt, QK, Vt);
    hipLaunchKernelGGL(k_flash,    dim3(512),    dim3(256), 0, stream, QK, Vt, attn);
    hipLaunchKernelGGL(k_gemm_out, dim3(1024),   dim3(128), 0, stream, attn, Wo2t, bo, out);
}

// Round 14
// 190.679 us; speedup vs baseline: 1.0448x; 1.0448x over previous
//
#include <hip/hip_runtime.h>
#include <math.h>

#define DIM 1024
#define NH 16
#define HD 64
#define TT 2048
#define NTOK 4096   // B*T

typedef __bf16 bf8v __attribute__((ext_vector_type(8)));
typedef float f4v __attribute__((ext_vector_type(4)));
typedef float f16v __attribute__((ext_vector_type(16)));
typedef unsigned short us8 __attribute__((ext_vector_type(8)));
typedef unsigned short us4 __attribute__((ext_vector_type(4)));
typedef unsigned int u4v __attribute__((ext_vector_type(4)));

static __device__ __forceinline__ unsigned short f2bf(float f) {
    unsigned int u = __float_as_uint(f);
    u += 0x7FFFu + ((u >> 16) & 1u);   // RNE
    return (unsigned short)(u >> 16);
}
static __device__ __forceinline__ bf8v ld8(const unsigned short* p) {
    return __builtin_bit_cast(bf8v, *(const us8*)p);
}
// async global->LDS, 16B per lane; HW dest = wave-uniform base + lane*16
static __device__ __forceinline__ void gl_lds(const unsigned short* g, unsigned short* l) {
    __builtin_amdgcn_global_load_lds((const __attribute__((address_space(1))) unsigned int*)(g),
                                     (__attribute__((address_space(3))) unsigned int*)(l), 16, 0, 0);
}

// ---------- fused prep: x->bf16 | W transpose->bf16 | rope table | zero Rm ----------
__global__ void k_prep(const float* __restrict__ x, unsigned short* __restrict__ xb,
                       const float* __restrict__ Wq, const float* __restrict__ Wk,
                       const float* __restrict__ Wv, unsigned short* __restrict__ wt,
                       float* __restrict__ rope, float* __restrict__ Rm) {
    int tid = threadIdx.x;
    int bb = blockIdx.x;
    if (bb < 4096) {                       // cast x (4 floats/thread)
        int i = bb * 256 + tid;
        float4 v = ((const float4*)x)[i];
        us4 o;
        o[0] = f2bf(v.x); o[1] = f2bf(v.y); o[2] = f2bf(v.z); o[3] = f2bf(v.w);
        *(us4*)&xb[i * 4] = o;
    } else if (bb < 7168) {                // transpose Wq|Wk|Wv
        __shared__ float tile[32][33];
        bb -= 4096;
        int z = bb >> 10, rem = bb & 1023;
        int bx = rem & 31, by = rem >> 5;
        const float* W = (z == 0) ? Wq : ((z == 1) ? Wk : Wv);
        int tx = tid & 31, ty = tid >> 5;   // (32, 8)
        int c0 = bx * 32, k0 = by * 32;
#pragma unroll
        for (int j = 0; j < 4; j++)
            tile[ty + j * 8][tx] = W[(k0 + ty + j * 8) * DIM + c0 + tx];
        __syncthreads();
        unsigned short* out = wt + z * DIM * DIM;
#pragma unroll
        for (int j = 0; j < 4; j++)
            out[(c0 + ty + j * 8) * DIM + k0 + tx] = f2bf(tile[tx][ty + j * 8]);
    } else if (bb < 7680) {                // rope [TT][HD]
        int i = (bb - 7168) * 256 + tid;
        int s = i >> 6, d = i & 63;
        float inv = exp2f(-(float)(d & 31) * (13.287712379549449f / 32.0f));
        float a = (float)s * inv;
        rope[i] = (d < 32) ? cosf(a) : sinf(a);
    } else {                               // zero Rm (4096 floats) for k_R atomics
        Rm[(bb - 7680) * 256 + tid] = 0.f;
    }
}

// ---------------- R = rope^T rope (64x64), 8x s-parallel blocks, atomic partials ----------------
__global__ void k_R(const float* __restrict__ rope, float* __restrict__ R) {
    __shared__ float red[256];
    int d = blockIdx.x & 63, sg = blockIdx.x >> 6;    // 64 d x 8 s-groups
    int e = threadIdx.x & 63, sl = threadIdx.x >> 6;
    const float* rp = rope + (sg * 256 + sl * 64) * 64;
    float acc = 0.f;
    for (int s = 0; s < 64; s++)
        acc += rp[s * 64 + d] * rp[s * 64 + e];
    red[threadIdx.x] = acc;
    __syncthreads();
    if (sl == 0)
        atomicAdd(&R[d * 64 + e], (red[e] + red[e + 64]) + (red[e + 128] + red[e + 192]));
}

// ------------- Wo2t[j][r] = sum_e R[d][e] * Wo[h*64+e][j],  r = h*64+d -------------
__global__ void k_wo2(const float* __restrict__ Wo, const float* __restrict__ R,
                      unsigned short* __restrict__ wo2t) {
    __shared__ float Ws[64 * 65];   // Ws[e][j]
    __shared__ float Rt[64 * 65];   // Rt[e][d] = R[d*64+e]
    int tid = threadIdx.x;
    int h = blockIdx.y, j0 = blockIdx.x * 64;
    for (int idx = tid; idx < 4096; idx += 256) {
        int e = idx >> 6, j = idx & 63;
        Ws[e * 65 + j] = Wo[(h * 64 + e) * DIM + j0 + j];
        Rt[e * 65 + j] = R[j * 64 + e];
    }
    __syncthreads();
    int d = tid & 63, jb = (tid >> 6) * 16;
    float acc[16] = {};
    for (int e = 0; e < 64; e++) {
        float r = Rt[e * 65 + d];
#pragma unroll
        for (int jj = 0; jj < 16; jj++)
            acc[jj] += r * Ws[e * 65 + jb + jj];
    }
#pragma unroll
    for (int jj = 0; jj < 16; jj++)
        wo2t[(j0 + jb + jj) * DIM + h * 64 + d] = f2bf(acc[jj]);
}

// ================= GEMM core (m97-style, round-10 tile config): BK=32, XOR-swizzled LDS =================
// LDS layout: row-major [*][32] bf16, 16B chunk q of row r stored at phys slot q^(r&3).
// Frag read for logical quarter `quad` uses qx = quad^(l16&3) -> bank-uniform.

// QKV projection v2: round-10 tiles (BM=BN=128, grid 24x32) + flash-proven DBUF counted-vmcnt:
// LDS double-buffered (2x As,Bs = 32KB), prologue stages tiles 0,1; loop top waits vmcnt(4)
// (never 0 mid-loop), STAGE(it+2) after barrier-2. Removes the per-iter vmcnt(0) L2-latency
// drain. Sync protocol byte-identical to k_flash (proven rounds 4/9/10).
__global__ __launch_bounds__(256, 3) void k_gemm_qkv(const unsigned short* __restrict__ A,
                                                     const unsigned short* __restrict__ Bt,
                                                     unsigned short* __restrict__ qk,
                                                     unsigned short* __restrict__ vt) {
    __shared__ unsigned short As[2][128 * 32];
    __shared__ unsigned short Bs[2][128 * 32];
    const int K = 1024;
    int tid = threadIdx.x;
    int lane = tid & 63, w = tid >> 6;
    int quad = lane >> 4, l16 = lane & 15;
    int m0 = blockIdx.y * 128, n0 = blockIdx.x * 128;
    int wm = (w >> 1) * 64, wn = (w & 1) * 64;

    // two 16B staging chunks per thread, lane-contiguous per wave
    int s0 = tid, s1 = 256 + tid;
    int r0 = s0 >> 2, cc0 = ((s0 & 3) ^ (r0 & 3)) * 8;
    int r1 = s1 >> 2, cc1 = ((s1 & 3) ^ (r1 & 3)) * 8;
    const unsigned short* Ag0 = A + (m0 + r0) * K + cc0;
    const unsigned short* Ag1 = A + (m0 + r1) * K + cc1;
    const unsigned short* Bg0 = Bt + (n0 + r0) * K + cc0;
    const unsigned short* Bg1 = Bt + (n0 + r1) * K + cc1;
    int qx = quad ^ (l16 & 3);

#define QSTAGE(t, buf) do {                                 \
        int kk_ = (t) * 32;                                 \
        gl_lds(Ag0 + kk_, &As[buf][s0 * 8]);                \
        gl_lds(Ag1 + kk_, &As[buf][s1 * 8]);                \
        gl_lds(Bg0 + kk_, &Bs[buf][s0 * 8]);                \
        gl_lds(Bg1 + kk_, &Bs[buf][s1 * 8]);                \
    } while (0)

    QSTAGE(0, 0);
    QSTAGE(1, 1);

    f4v acc[4][4] = {};
    for (int it = 0; it < 32; it++) {
        int cur = it & 1;
        if (it == 31) { asm volatile("s_waitcnt vmcnt(0)" ::: "memory"); }
        else          { asm volatile("s_waitcnt vmcnt(4)" ::: "memory"); }
        __builtin_amdgcn_s_barrier();
        asm volatile("" ::: "memory");
        bf8v af[4], bf[4];
#pragma unroll
        for (int mt = 0; mt < 4; mt++)
            af[mt] = ld8(&As[cur][(wm + mt * 16 + l16) * 32 + qx * 8]);
#pragma unroll
        for (int nt = 0; nt < 4; nt++)
            bf[nt] = ld8(&Bs[cur][(wn + nt * 16 + l16) * 32 + qx * 8]);
#pragma unroll
        for (int mt = 0; mt < 4; mt++)
#pragma unroll
            for (int nt = 0; nt < 4; nt++)
                acc[mt][nt] = __builtin_amdgcn_mfma_f32_16x16x32_bf16(af[mt], bf[nt], acc[mt][nt], 0, 0, 0);
        __builtin_amdgcn_s_barrier();
        asm volatile("" ::: "memory");
        if (it < 30) QSTAGE(it + 2, cur);
    }
#undef QSTAGE
#pragma unroll
    for (int mt = 0; mt < 4; mt++) {
#pragma unroll
        for (int nt = 0; nt < 4; nt++) {
            int gc = n0 + wn + nt * 16 + l16;
            int h = (gc >> 6) & 15;
            int d = gc & 63;
            if (gc < 2048) {             // Q or K: [mtx][B][H][T][64]; Q pre-scaled by c1
                float qs = (gc < 1024) ? 0.18033688011111793f : 1.0f;
                int mtx = gc >> 10;
                unsigned short* base = qk + mtx * (NTOK * DIM);
#pragma unroll
                for (int r = 0; r < 4; r++) {
                    int gm = m0 + wm + mt * 16 + quad * 4 + r;
                    int b = gm >> 11, t = gm & 2047;
                    base[((b * NH + h) * TT + t) * HD + d] = f2bf(acc[mt][nt][r] * qs);
                }
            } else {                     // V: transposed [B][H][64][T]
                int gm0 = m0 + wm + mt * 16 + quad * 4;
                int b = gm0 >> 11, t = gm0 & 2047;
                us4 ov;
#pragma unroll
                for (int r = 0; r < 4; r++)
                    ov[r] = f2bf(acc[mt][nt][r]);
                *(us4*)&vt[(((b * NH + h) * HD) + d) * TT + t] = ov;
            }
        }
    }
}

// Output projection v4 (round-10 proven): plain GEMM, XCD-grouped BM=64 decode.
__global__ __launch_bounds__(256, 2) void k_gemm_out(const unsigned short* __restrict__ A,
                                                     const unsigned short* __restrict__ Bt,
                                                     const float* __restrict__ bo,
                                                     float* __restrict__ out) {
    __shared__ unsigned short As[64 * 32];
    __shared__ unsigned short Bs[128 * 32];
    const int K = 1024;
    int tid = threadIdx.x;
    int lane = tid & 63, w = tid >> 6;
    int quad = lane >> 4, l16 = lane & 15;
    int bid = blockIdx.x;
    int xcd = bid & 7, slot = bid >> 3;
    int y = xcd * 8 + (slot & 7);        // 0..63 m-panel
    int x = slot >> 3;                   // 0..7  n-panel
    int m0 = y * 64, n0 = x * 128;
    int wn = w * 32;                     // wave covers 64 rows x 32 cols

    int rr = tid >> 2, cc = ((tid & 3) ^ (rr & 3)) * 8;
    const unsigned short* Ag0 = A + (m0 + rr) * K + cc;
    const unsigned short* Bg0 = Bt + (n0 + rr) * K + cc;
    const unsigned short* Bg1 = Bt + (n0 + 64 + rr) * K + cc;
    int qx = quad ^ (l16 & 3);

    f4v acc[4][2] = {};
    for (int k0 = 0; k0 < K; k0 += 32) {
        __syncthreads();                       // prior iter frag reads done
        gl_lds(Ag0 + k0, &As[tid * 8]);
        gl_lds(Bg0 + k0, &Bs[tid * 8]);
        gl_lds(Bg1 + k0, &Bs[(256 + tid) * 8]);
        __syncthreads();                       // drains vmcnt -> tiles in LDS
        bf8v af[4], bf[2];
#pragma unroll
        for (int mt = 0; mt < 4; mt++)
            af[mt] = ld8(&As[(mt * 16 + l16) * 32 + qx * 8]);
#pragma unroll
        for (int nt = 0; nt < 2; nt++)
            bf[nt] = ld8(&Bs[(wn + nt * 16 + l16) * 32 + qx * 8]);
#pragma unroll
        for (int mt = 0; mt < 4; mt++)
#pragma unroll
            for (int nt = 0; nt < 2; nt++)
                acc[mt][nt] = __builtin_amdgcn_mfma_f32_16x16x32_bf16(af[mt], bf[nt], acc[mt][nt], 0, 0, 0);
    }
#pragma unroll
    for (int mt = 0; mt < 4; mt++) {
#pragma unroll
        for (int nt = 0; nt < 2; nt++) {
            int gc = n0 + wn + nt * 16 + l16;
            float bias = bo[gc];
#pragma unroll
            for (int r = 0; r < 4; r++) {
                int gm = m0 + mt * 16 + quad * 4 + r;
                out[gm * DIM + gc] = acc[mt][nt][r] + bias;
            }
        }
    }
}

// ================= flash attention v6 (round-10 proven): full-KV, direct normalized output =================
// Each block iterates all 2048 keys (32 iters); softmax rows complete in-register -> normalize
// by rcp(lsum), write FINAL bf16 attn directly. Grid 512 (2 blocks/CU). UNCHANGED from round 10.
__global__ __launch_bounds__(256, 2) void k_flash(const unsigned short* __restrict__ qk,
                                                  const unsigned short* __restrict__ vt,
                                                  unsigned short* __restrict__ attn) {
    __shared__ unsigned short Ks[2][64 * 64];
    __shared__ unsigned short Vs[2][64 * 64];
    int tid = threadIdx.x;
    int lane = tid & 63, w = tid >> 6;
    int q31 = lane & 31, hi = lane >> 5;
    int bid = blockIdx.x;
    int xcd = bid & 7, sl = bid >> 3;
    int bh = xcd * 4 + (sl & 3);
    int qt = sl >> 2;                    // 0..15

    const unsigned short* Qg = qk + bh * (TT * HD);
    const unsigned short* Kg = qk + NTOK * DIM + bh * (TT * HD);
    const unsigned short* Vg = vt + bh * (HD * TT);

    // Q B-frag (k=dim): lane n=q31 holds Q[qrow][16*ks + 8*hi + j]
    int qrow = qt * 128 + w * 32 + q31;
    bf8v qf[4];
#pragma unroll
    for (int ks = 0; ks < 4; ks++)
        qf[ks] = ld8(Qg + qrow * HD + ks * 16 + hi * 8);

    // staging: 512 chunks of 16B per tile; thread stages chunks tid and 256+tid.
    // chunk idx -> row r=idx>>3, phys slot p=idx&7, logical chunk c=p^(r&7) (involution).
    int r0 = tid >> 3, sw = (tid & 7) ^ (r0 & 7);
    int offK0 = r0 * HD + sw * 8, offK1 = offK0 + 32 * HD;
    int offV0 = r0 * TT + sw * 8, offV1 = offV0 + 32 * TT;
    int dst0 = tid * 8, dst1 = dst0 + 2048;

#define STAGE(tile, bufsel) do {                                  \
        const unsigned short* kb_ = Kg + (tile) * 64 * HD;        \
        const unsigned short* vb_ = Vg + (tile) * 64;             \
        gl_lds(kb_ + offK0, &Ks[bufsel][dst0]);                   \
        gl_lds(kb_ + offK1, &Ks[bufsel][dst1]);                   \
        gl_lds(vb_ + offV0, &Vs[bufsel][dst0]);                   \
        gl_lds(vb_ + offV1, &Vs[bufsel][dst1]);                   \
    } while (0)

    STAGE(0, 0);
    STAGE(1, 1);

    f16v oacc[2] = {};               // [mtd] O^T dim tiles
    float lsg = 0.f;
    int xsw = q31 & 7;

    for (int it = 0; it < 32; it++) {
        int cur = it & 1;
        if (it == 31) { asm volatile("s_waitcnt vmcnt(0)" ::: "memory"); }
        else          { asm volatile("s_waitcnt vmcnt(4)" ::: "memory"); }
        __builtin_amdgcn_s_barrier();
        asm volatile("" ::: "memory");

        const unsigned short* Kb = Ks[cur];
        const unsigned short* Vb = Vs[cur];

        // K frags + QK^T: S^T[key][qrow], 2 key tiles x K=64 (4 steps)
        bf8v kf0[4], kf1[4];
#pragma unroll
        for (int ks = 0; ks < 4; ks++) {
            kf0[ks] = ld8(&Kb[(q31) * 64 + ((2 * ks + hi) ^ xsw) * 8]);
            kf1[ks] = ld8(&Kb[(32 + q31) * 64 + ((2 * ks + hi) ^ xsw) * 8]);
        }
        f16v s0 = {}, s1 = {};
#pragma unroll
        for (int ks = 0; ks < 4; ks++) {
            s0 = __builtin_amdgcn_mfma_f32_32x32x16_bf16(kf0[ks], qf[ks], s0, 0, 0, 0);
            s1 = __builtin_amdgcn_mfma_f32_32x32x16_bf16(kf1[ks], qf[ks], s1, 0, 0, 0);
        }

        // V^T A-frags (ds_read latency hides under softmax chunks)
        bf8v vf[2][4];
#pragma unroll
        for (int kk = 0; kk < 4; kk++) {
            vf[0][kk] = ld8(&Vb[(q31) * 64 + ((2 * kk + hi) ^ xsw) * 8]);
            vf[1][kk] = ld8(&Vb[(32 + q31) * 64 + ((2 * kk + hi) ^ xsw) * 8]);
        }

        // chunk-fused softmax -> PV. Per 16-key chunk kk = mt*2+sub:
        // reg r of s_mt holds S^T[key = 32mt + (r&3)+8(r>>2)+4hi][qrow]; p = 2^s (Q pre-scaled).
        // cvt_pk pairs -> e0..e3 (keys {0,1},{2,3},{8,9},{10,11}+4hi); swap(e0,e2)+swap(e1,e3)
        // -> P^T B-frag words (k=8hi+j). Then 2 PV MFMAs for this chunk overlap next chunk VALU.
#pragma unroll
        for (int mt = 0; mt < 2; mt++) {
#pragma unroll
            for (int sub = 0; sub < 2; sub++) {
                const f16v& s = mt ? s1 : s0;
                float pe[8];
#pragma unroll
                for (int j = 0; j < 8; j++)
                    pe[j] = __builtin_amdgcn_exp2f(s[sub * 8 + j]);
                float t01 = pe[0] + pe[1], t23 = pe[2] + pe[3];
                float t45 = pe[4] + pe[5], t67 = pe[6] + pe[7];
                lsg += (t01 + t23) + (t45 + t67);
                unsigned int e0, e1, e2, e3;
                asm("v_cvt_pk_bf16_f32 %0, %1, %2" : "=v"(e0) : "v"(pe[0]), "v"(pe[1]));
                asm("v_cvt_pk_bf16_f32 %0, %1, %2" : "=v"(e1) : "v"(pe[2]), "v"(pe[3]));
                asm("v_cvt_pk_bf16_f32 %0, %1, %2" : "=v"(e2) : "v"(pe[4]), "v"(pe[5]));
                asm("v_cvt_pk_bf16_f32 %0, %1, %2" : "=v"(e3) : "v"(pe[6]), "v"(pe[7]));
                asm("v_permlane32_swap_b32 %0, %1" : "+v"(e0), "+v"(e2));
                asm("v_permlane32_swap_b32 %0, %1" : "+v"(e1), "+v"(e3));
                u4v pv = {e0, e1, e2, e3};
                bf8v pb = __builtin_bit_cast(bf8v, pv);
                int kk = mt * 2 + sub;
                oacc[0] = __builtin_amdgcn_mfma_f32_32x32x16_bf16(vf[0][kk], pb, oacc[0], 0, 0, 0);
                oacc[1] = __builtin_amdgcn_mfma_f32_32x32x16_bf16(vf[1][kk], pb, oacc[1], 0, 0, 0);
            }
        }

        __builtin_amdgcn_s_barrier();
        asm volatile("" ::: "memory");
        if (it < 30) STAGE(it + 2, cur);
    }
#undef STAGE

    // epilogue: complete row sums -> normalize in-register, write FINAL bf16 attn
    float lsum = lsg + __shfl_xor(lsg, 32, 64);
    float inv = __builtin_amdgcn_rcpf(lsum);
    int b = bh >> 4, h = bh & 15;
    unsigned short* dst = attn + ((b * TT) + qrow) * DIM + h * HD + hi * 4;
#pragma unroll
    for (int mtd = 0; mtd < 2; mtd++) {
#pragma unroll
        for (int g4 = 0; g4 < 4; g4++) {
            us4 ov;
#pragma unroll
            for (int r = 0; r < 4; r++)
                ov[r] = f2bf(oacc[mtd][g4 * 4 + r] * inv);   // dim = 32*mtd + 8*g4 + 4*hi + r
            *(us4*)&dst[mtd * 32 + g4 * 8] = ov;
        }
    }
}

extern "C" void kernel_launch(void* const* d_in, const int* in_sizes, int n_in,
                              void* d_out, int out_size, void* d_ws, size_t ws_size,
                              hipStream_t stream) {
    const float* x  = (const float*)d_in[0];
    const float* Wq = (const float*)d_in[1];
    const float* Wk = (const float*)d_in[2];
    const float* Wv = (const float*)d_in[3];
    const float* Wo = (const float*)d_in[4];
    const float* bo = (const float*)d_in[5];
    float* out = (float*)d_out;
    char* ws = (char*)d_ws;

    // attn (8MB) aliases Xb: Xb dead after k_gemm_qkv, flash writes attn after.
    unsigned short* Xb    = (unsigned short*)(ws);                 //  8 MB
    unsigned short* Wqkvt = (unsigned short*)(ws + 8388608);       //  6 MB
    unsigned short* attn  = (unsigned short*)(ws);                 //  8 MB (aliases Xb)
    unsigned short* QK    = (unsigned short*)(ws + 16777216);      // 16 MB (Q then K)
    unsigned short* Vt    = (unsigned short*)(ws + 33554432);      //  8 MB (V transposed)
    unsigned short* Wo2t  = (unsigned short*)(ws + 50331648);      //  2 MB
    float*          rope  = (float*)(ws + 52428800);               // 512 KB
    float*          Rm    = (float*)(ws + 52953088);               // 16 KB

    hipLaunchKernelGGL(k_prep,     dim3(7696),   dim3(256), 0, stream, x, Xb, Wq, Wk, Wv, Wqkvt, rope, Rm);
    hipLaunchKernelGGL(k_R,        dim3(512),    dim3(256), 0, stream, rope, Rm);
    hipLaunchKernelGGL(k_wo2,      dim3(16, 16), dim3(256), 0, stream, Wo, Rm, Wo2t);
    hipLaunchKernelGGL(k_gemm_qkv, dim3(24, 32), dim3(256), 0, stream, Xb, Wqkvt, QK, Vt);
    hipLaunchKernelGGL(k_flash,    dim3(512),    dim3(256), 0, stream, QK, Vt, attn);
    hipLaunchKernelGGL(k_gemm_out, dim3(512),    dim3(256), 0, stream, attn, Wo2t, bo, out);
}